// Round 14
// baseline (89.833 us; speedup 1.0000x reference)
//
#include <hip/hip_runtime.h>
#include <math.h>

// Problem constants (fixed by the reference)
#define N_NODES 50000
#define N_EDGES 800000
#define FN_DIM 16
#define HD 64
#define T_CAP 8192     // cap on |need1| (measured ~355) = layer-0 targets
#define T2_CAP 512     // cap on |need2| (measured ~17)  = layer-1 targets
#define MAXDEG 128     // cap on in-degree (Poisson(16))
#define NW 16          // waves per block (1024 threads)

// ---------- wave-64 helpers ----------
__device__ __forceinline__ float wsum64(float v) {
    #pragma unroll
    for (int o = 1; o < 64; o <<= 1) v += __shfl_xor(v, o);
    return v;
}
__device__ __forceinline__ float wmax64(float v) {
    #pragma unroll
    for (int o = 1; o < 64; o <<= 1) v = fmaxf(v, __shfl_xor(v, o));
    return v;
}
__device__ __forceinline__ float lrelu02(float v) { return v > 0.f ? v : 0.2f * v; }

// ---------- zero the flag/counter zone ----------
__global__ void k_zero(int4* __restrict__ p, int n4) {
    int i = blockIdx.x * blockDim.x + threadIdx.x;
    if (i < n4) p[i] = make_int4(0, 0, 0, 0);
}

// ---------- scan A: edges into node 0 -> eb3, seed/mark need2 & need1 (+lists/idx) ----------
__global__ void k_scanA(const int* __restrict__ ei,
                        int* need1, int* need2, int* list1, int* list2,
                        int* idx1, int* idx2, int* cnt, int* eb3, int* deg3) {
    int e = blockIdx.x * blockDim.x + threadIdx.x;
    if (e == 0) {   // seed node 0 (same dedup protocol as edge hits)
        if (atomicExch(&need2[0], 1) == 0) { int p = atomicAdd(&cnt[1], 1); if (p < T2_CAP) { list2[p] = 0; idx2[0] = p; } }
        if (atomicExch(&need1[0], 1) == 0) { int p = atomicAdd(&cnt[0], 1); if (p < T_CAP)  { list1[p] = 0; idx1[0] = p; } }
    }
    if (e >= N_EDGES) return;
    if (ei[N_EDGES + e] == 0) {
        int s = ei[e];
        int p = atomicAdd(deg3, 1); if (p < MAXDEG) eb3[p] = s;
        if (atomicExch(&need2[s], 1) == 0) { int q = atomicAdd(&cnt[1], 1); if (q < T2_CAP) { list2[q] = s; idx2[s] = q; } }
        if (atomicExch(&need1[s], 1) == 0) { int q = atomicAdd(&cnt[0], 1); if (q < T_CAP)  { list1[q] = s; idx1[s] = q; } }
    }
}

// ---------- scan B: edges into need2 -> eb2 buckets; mark need1 sources ----------
__global__ void k_scanB(const int* __restrict__ ei, const int* __restrict__ need2,
                        const int* __restrict__ idx2,
                        int* need1, int* list1, int* idx1, int* cnt,
                        int* eb2, int* deg2) {
    int e = blockIdx.x * blockDim.x + threadIdx.x;
    if (e >= N_EDGES) return;
    int d = ei[N_EDGES + e];
    if (need2[d]) {
        int s = ei[e];
        unsigned t = (unsigned)idx2[d];
        if (t < T2_CAP) { int p = atomicAdd(&deg2[t], 1); if (p < MAXDEG) eb2[t * MAXDEG + p] = s; }
        if (atomicExch(&need1[s], 1) == 0) { int q = atomicAdd(&cnt[0], 1); if (q < T_CAP) { list1[q] = s; idx1[s] = q; } }
    }
}

// ---------- scan C: edges into need1 -> eb1 buckets ----------
__global__ void k_scanC(const int* __restrict__ ei, const int* __restrict__ need1,
                        const int* __restrict__ idx1, int* eb1, int* deg1) {
    int e = blockIdx.x * blockDim.x + threadIdx.x;
    if (e >= N_EDGES) return;
    int d = ei[N_EDGES + e];
    if (need1[d]) {
        unsigned t = (unsigned)idx1[d];
        if (t < T_CAP) { int p = atomicAdd(&deg1[t], 1); if (p < MAXDEG) eb1[t * MAXDEG + p] = ei[e]; }
    }
}

// ---------- node feature: layer 0 encodes from x, later layers load h ----------
template<int LM>
__device__ __forceinline__ float node_h(int i, int lane,
    const float* __restrict__ x, const float* __restrict__ Wn, const float* __restrict__ bn,
    const float* __restrict__ gn, const float* __restrict__ betan,
    const float* __restrict__ hin) {
    if (LM == 0) {
        float acc = bn[lane];
        #pragma unroll
        for (int k = 0; k < FN_DIM; k++) acc += x[i * FN_DIM + k] * Wn[k * HD + lane];
        float v = fmaxf(acc, 0.f);
        float mu = wsum64(v) * (1.f / 64.f);
        float d = v - mu;
        float var = wsum64(d * d) * (1.f / 64.f);
        return d * rsqrtf(var + 1e-5f) * gn[lane] + betan[lane];
    } else {
        return hin[i * HD + lane];
    }
}

// ---------- heads (wave 0 only), writes out[0..32] ----------
__device__ __forceinline__ void heads_eval(float hv, int lane,
    const float* __restrict__ Wq1, const float* __restrict__ bq1,
    const float* __restrict__ gq, const float* __restrict__ betaq,
    const float* __restrict__ Wq2, const float* __restrict__ bq2,
    const float* __restrict__ Wv1, const float* __restrict__ bv1,
    const float* __restrict__ gv, const float* __restrict__ betav,
    const float* __restrict__ Wv2, const float* __restrict__ bv2,
    float* __restrict__ out) {
    float acc = bq1[lane];
    #pragma unroll 8
    for (int k = 0; k < 64; k++) acc += __shfl(hv, k) * Wq1[k * 64 + lane];
    float r = fmaxf(acc, 0.f);
    float mu = wsum64(r) * (1.f / 64.f);
    float d = r - mu;
    float var = wsum64(d * d) * (1.f / 64.f);
    float tq = d * rsqrtf(var + 1e-5f) * gq[lane] + betaq[lane];
    float accv = bv1[lane];
    #pragma unroll 8
    for (int k = 0; k < 64; k++) accv += __shfl(hv, k) * Wv1[k * 64 + lane];
    float rv = fmaxf(accv, 0.f);
    float muv = wsum64(rv) * (1.f / 64.f);
    float dv = rv - muv;
    float varv = wsum64(dv * dv) * (1.f / 64.f);
    float tv = dv * rsqrtf(varv + 1e-5f) * gv[lane] + betav[lane];
    int s = lane & 31;
    float q = bq2[s];
    #pragma unroll 8
    for (int k = 0; k < 64; k++) q += __shfl(tq, k) * Wq2[k * 32 + s];
    if (lane < 32) out[lane] = q;
    float vsum = wsum64(tv * Wv2[lane]);
    if (lane == 0) out[32] = vsum + bv2[0];
}

// ---------- fully fused layer: block per target, 16 waves, 1 edge/wave/pass ----------
// r13 body with doubled wave-level parallelism again (same inner-loop codegen);
// LM>=1 stages the four weight matrices in LDS.
template<int LM>
__global__ __launch_bounds__(1024) void k_layer(
    const float* __restrict__ x, const float* __restrict__ Wn, const float* __restrict__ bn,
    const float* __restrict__ gn, const float* __restrict__ betan,
    const float* __restrict__ hin,
    const float* __restrict__ Wc1, const float* __restrict__ bc1,
    const float* __restrict__ Wc2, const float* __restrict__ bc2,
    const float* __restrict__ Wg, const float* __restrict__ atts, const float* __restrict__ attd,
    const float* __restrict__ bgv,
    const int* __restrict__ tlist, const int* __restrict__ cntp, int tcap,
    const int* __restrict__ eb, const int* __restrict__ deg,
    float* __restrict__ hout,
    const float* __restrict__ Wq1, const float* __restrict__ bq1,
    const float* __restrict__ gq, const float* __restrict__ betaq,
    const float* __restrict__ Wq2, const float* __restrict__ bq2,
    const float* __restrict__ Wv1, const float* __restrict__ bv1,
    const float* __restrict__ gv, const float* __restrict__ betav,
    const float* __restrict__ Wv2, const float* __restrict__ bv2)
{
    __shared__ float ht[64], ut[64], xgt[64];
    __shared__ float scr[NW][64];       // per-wave 1-edge vector scratch
    __shared__ float xgc[MAXDEG][64];   // per-edge xg cache
    __shared__ float ec[MAXDEG];        // per-edge attention logit
    __shared__ float redA[NW][64], redB[NW][64];
    __shared__ float sws[NW];
    __shared__ float sA[2];             // a_s[t], a_d[t]
    __shared__ float sEm;
    // staged weights (LM>=1 only): [0:4096)=Wc1a [4096:8192)=Wc1b [8192:12288)=Wc2 [12288:16384)=Wg
    __shared__ float wst[(LM == 0) ? 4 : 16384];

    int lane = threadIdx.x & 63;
    int wv = threadIdx.x >> 6;          // 0..15
    int ntgt = (LM == 2) ? 1 : min(cntp[0], tcap);

    if constexpr (LM != 0) {
        float4* d4 = (float4*)wst;
        const float4* s1 = (const float4*)Wc1;   // 2048 float4 = both halves
        const float4* s2 = (const float4*)Wc2;
        const float4* s3 = (const float4*)Wg;
        for (int i = threadIdx.x; i < 1024; i += 1024) {
            d4[i]        = s1[i];
            d4[1024 + i] = s1[1024 + i];
            d4[2048 + i] = s2[i];
            d4[3072 + i] = s3[i];
        }
        __syncthreads();
    }

    for (int w = blockIdx.x; w < ntgt; w += gridDim.x) {
        int t = (LM == 2) ? 0 : tlist[w];
        if (wv == 0) {
            float h = node_h<LM>(t, lane, x, Wn, bn, gn, betan, hin);
            ht[lane] = h;
            float u = bc1[lane], xg = 0.f;
            if constexpr (LM != 0) {
                #pragma unroll 4
                for (int k = 0; k < 64; k++) {
                    float b = ht[k];
                    u  += b * wst[k * 64 + lane];
                    xg += b * wst[12288 + k * 64 + lane];
                }
            } else {
                #pragma unroll 4
                for (int k = 0; k < 64; k++) {
                    float b = ht[k];
                    u  += b * Wc1[k * 64 + lane];
                    xg += b * Wg[k * 64 + lane];
                }
            }
            ut[lane] = u; xgt[lane] = xg;
            float a_st = wsum64(xg * atts[lane]);
            float a_dt = wsum64(xg * attd[lane]);
            if (lane == 0) { sA[0] = a_st; sA[1] = a_dt; }
        }
        __syncthreads();
        int dg = deg[(LM == 2) ? 0 : w]; if (dg > MAXDEG) dg = MAXDEG;
        float a_dt = sA[1];
        float aggw = -INFINITY;

        for (int j0 = wv; j0 < dg; j0 += NW) {
            int s = eb[w * MAXDEG + j0];
            scr[wv][lane] = node_h<LM>(s, lane, x, Wn, bn, gn, betan, hin);
            float v = 0.f, g = 0.f;
            if constexpr (LM != 0) {
                #pragma unroll 4
                for (int k = 0; k < 64; k++) {
                    float b = scr[wv][k];
                    v += b * wst[4096 + k * 64 + lane];
                    g += b * wst[12288 + k * 64 + lane];
                }
            } else {
                #pragma unroll 4
                for (int k = 0; k < 64; k++) {
                    float b = scr[wv][k];
                    v += b * Wc1[(64 + k) * 64 + lane];
                    g += b * Wg[k * 64 + lane];
                }
            }
            float hs = scr[wv][lane];
            float hid = fmaxf(ut[lane] + v, 0.f);
            scr[wv][lane] = hid;
            float m = bc2[lane];
            if constexpr (LM != 0) {
                #pragma unroll 4
                for (int k = 0; k < 64; k++) m += scr[wv][k] * wst[8192 + k * 64 + lane];
            } else {
                #pragma unroll 4
                for (int k = 0; k < 64; k++) m += scr[wv][k] * Wc2[k * 64 + lane];
            }
            aggw = fmaxf(aggw, m);
            xgc[j0][lane] = g;
            float a_ss = wsum64(g * atts[lane]);
            if (lane == 0) ec[j0] = lrelu02(a_ss + a_dt);
            scr[wv][lane] = hs;   // keep hs? not needed further; harmless restore
        }
        redA[wv][lane] = aggw;
        __syncthreads();

        if (wv == 0) {
            float es = lrelu02(sA[0] + sA[1]);
            float mm = es;
            for (int j = lane; j < dg; j += 64) mm = fmaxf(mm, ec[j]);
            mm = wmax64(mm);
            if (lane == 0) sEm = mm;
        }
        __syncthreads();
        float em = sEm;
        float attv = 0.f, wsv = 0.f;
        for (int j = wv; j < dg; j += NW) {
            float wj = expf(ec[j] - em);
            attv += wj * xgc[j][lane];
            wsv += wj;
        }
        redB[wv][lane] = attv;
        if (lane == 0) sws[wv] = wsv;
        __syncthreads();

        if (wv == 0) {
            float agg = redA[0][lane];
            #pragma unroll
            for (int q = 1; q < NW; q++) agg = fmaxf(agg, redA[q][lane]);
            if (dg == 0) agg = 0.f;   // PyG scatter-max: empty segment -> 0
            float es = lrelu02(sA[0] + sA[1]);
            float wself = expf(es - em);
            float att = wself * xgt[lane];
            float wsum = wself;
            #pragma unroll
            for (int q = 0; q < NW; q++) { att += redB[q][lane]; wsum += sws[q]; }
            float hv = fmaxf(ht[lane] + agg + att / wsum + bgv[lane], 0.f);
            if (LM == 2) {
                heads_eval(hv, lane, Wq1, bq1, gq, betaq, Wq2, bq2,
                           Wv1, bv1, gv, betav, Wv2, bv2, hout);
            } else {
                hout[t * HD + lane] = hv;
            }
        }
        __syncthreads();
    }
}

extern "C" void kernel_launch(void* const* d_in, const int* in_sizes, int n_in,
                              void* d_out, int out_size, void* d_ws, size_t ws_size,
                              hipStream_t stream) {
    const float* x        = (const float*)d_in[0];
    const int*   ei       = (const int*)d_in[1];
    // d_in[2] edge_attr and d_in[7..10] (edge encoder) are dead code in the reference
    const float* Wn       = (const float*)d_in[3];
    const float* bn       = (const float*)d_in[4];
    const float* gn       = (const float*)d_in[5];
    const float* betan    = (const float*)d_in[6];
    const float* Wc1      = (const float*)d_in[11];
    const float* bc1      = (const float*)d_in[12];
    const float* Wc2      = (const float*)d_in[13];
    const float* bc2      = (const float*)d_in[14];
    const float* Wg       = (const float*)d_in[15];
    const float* att_src  = (const float*)d_in[16];
    const float* att_dst  = (const float*)d_in[17];
    const float* bg       = (const float*)d_in[18];
    const float* Wq1      = (const float*)d_in[19];
    const float* bq1      = (const float*)d_in[20];
    const float* gq       = (const float*)d_in[21];
    const float* betaq    = (const float*)d_in[22];
    const float* Wq2      = (const float*)d_in[23];
    const float* bq2      = (const float*)d_in[24];
    const float* Wv1      = (const float*)d_in[25];
    const float* bv1      = (const float*)d_in[26];
    const float* gv       = (const float*)d_in[27];
    const float* betav    = (const float*)d_in[28];
    const float* Wv2      = (const float*)d_in[29];
    const float* bv2      = (const float*)d_in[30];

    // ---- workspace layout (identical ordering to r13)
    float* hB   = (float*)d_ws;                      // h1, N*64
    float* hA   = hB + (size_t)N_NODES * HD;         // h2, N*64
    int* need1  = (int*)(hA + (size_t)N_NODES * HD); // zero-zone start (16B aligned)
    int* need2  = need1 + N_NODES;
    int* deg1   = need2 + N_NODES;                   // T_CAP
    int* deg2   = deg1 + T_CAP;                      // T2_CAP
    int* deg3   = deg2 + T2_CAP;                     // 4
    int* cnt    = deg3 + 4;                          // 8   (zero-zone end)
    int* idx1   = cnt + 8;                           // N
    int* idx2   = idx1 + N_NODES;                    // N
    int* list1  = idx2 + N_NODES;                    // T_CAP
    int* list2  = list1 + T_CAP;                     // T2_CAP
    int* eb1    = list2 + T2_CAP;                    // T_CAP*MAXDEG
    int* eb2    = eb1 + (size_t)T_CAP * MAXDEG;      // T2_CAP*MAXDEG
    int* eb3    = eb2 + (size_t)T2_CAP * MAXDEG;     // MAXDEG

    const int zero_ints = 2 * N_NODES + T_CAP + T2_CAP + 12;   // 108716, /4 exact
    const int n4 = zero_ints / 4;                    // 27179 int4
    const int EB = (N_EDGES + 255) / 256;            // 3125 blocks

    k_zero<<<(n4 + 255) / 256, 256, 0, stream>>>((int4*)need1, n4);
    k_scanA<<<EB, 256, 0, stream>>>(ei, need1, need2, list1, list2,
                                    idx1, idx2, cnt, eb3, deg3);
    k_scanB<<<EB, 256, 0, stream>>>(ei, need2, idx2,
                                    need1, list1, idx1, cnt, eb2, deg2);
    k_scanC<<<EB, 256, 0, stream>>>(ei, need1, idx1, eb1, deg1);

    // layer 0: targets list1 (~355), sources encoded from x on the fly -> hB
    k_layer<0><<<512, 1024, 0, stream>>>(
        x, Wn, bn, gn, betan, (const float*)nullptr,
        Wc1 + 0 * 2 * HD * HD, bc1 + 0 * HD, Wc2 + 0 * HD * HD, bc2 + 0 * HD,
        Wg + 0 * HD * HD, att_src + 0 * HD, att_dst + 0 * HD, bg + 0 * HD,
        list1, cnt + 0, T_CAP, eb1, deg1, hB,
        Wq1, bq1, gq, betaq, Wq2, bq2, Wv1, bv1, gv, betav, Wv2, bv2);

    // layer 1: targets list2 (~17), h from hB -> hA
    k_layer<1><<<64, 1024, 0, stream>>>(
        x, Wn, bn, gn, betan, hB,
        Wc1 + 1 * 2 * HD * HD, bc1 + 1 * HD, Wc2 + 1 * HD * HD, bc2 + 1 * HD,
        Wg + 1 * HD * HD, att_src + 1 * HD, att_dst + 1 * HD, bg + 1 * HD,
        list2, cnt + 1, T2_CAP, eb2, deg2, hA,
        Wq1, bq1, gq, betaq, Wq2, bq2, Wv1, bv1, gv, betav, Wv2, bv2);

    // layer 2: target {0}, h from hA -> heads -> d_out
    k_layer<2><<<1, 1024, 0, stream>>>(
        x, Wn, bn, gn, betan, hA,
        Wc1 + 2 * 2 * HD * HD, bc1 + 2 * HD, Wc2 + 2 * HD * HD, bc2 + 2 * HD,
        Wg + 2 * HD * HD, att_src + 2 * HD, att_dst + 2 * HD, bg + 2 * HD,
        (const int*)nullptr, cnt + 1, 1, eb3, deg3, (float*)d_out,
        Wq1, bq1, gq, betaq, Wq2, bq2, Wv1, bv1, gv, betav, Wv2, bv2);
}

// Round 15
// 82.460 us; speedup vs baseline: 1.0894x; 1.0894x over previous
//
#include <hip/hip_runtime.h>
#include <math.h>

// Problem constants (fixed by the reference)
#define N_NODES 50000
#define N_EDGES 800000
#define FN_DIM 16
#define HD 64
#define T_CAP 8192     // cap on |need1| (measured ~355) = layer-0 targets
#define T2_CAP 512     // cap on |need2| (measured ~17)  = layer-1 targets
#define MAXDEG 128     // cap on in-degree (Poisson(16))
#define NW 8           // waves per block (512 threads) — measured optimum (r12=4:95us, r13=8:82.8us, r14=16:89.8us)

// ---------- wave-64 helpers ----------
__device__ __forceinline__ float wsum64(float v) {
    #pragma unroll
    for (int o = 1; o < 64; o <<= 1) v += __shfl_xor(v, o);
    return v;
}
__device__ __forceinline__ float wmax64(float v) {
    #pragma unroll
    for (int o = 1; o < 64; o <<= 1) v = fmaxf(v, __shfl_xor(v, o));
    return v;
}
__device__ __forceinline__ float lrelu02(float v) { return v > 0.f ? v : 0.2f * v; }

// ---------- zero the flag/counter zone ----------
__global__ void k_zero(int4* __restrict__ p, int n4) {
    int i = blockIdx.x * blockDim.x + threadIdx.x;
    if (i < n4) p[i] = make_int4(0, 0, 0, 0);
}

// ---------- scan A: edges into node 0 -> eb3, seed/mark need2 & need1 (+lists/idx) ----------
__global__ void k_scanA(const int* __restrict__ ei,
                        int* need1, int* need2, int* list1, int* list2,
                        int* idx1, int* idx2, int* cnt, int* eb3, int* deg3) {
    int e = blockIdx.x * blockDim.x + threadIdx.x;
    if (e == 0) {   // seed node 0 (same dedup protocol as edge hits)
        if (atomicExch(&need2[0], 1) == 0) { int p = atomicAdd(&cnt[1], 1); if (p < T2_CAP) { list2[p] = 0; idx2[0] = p; } }
        if (atomicExch(&need1[0], 1) == 0) { int p = atomicAdd(&cnt[0], 1); if (p < T_CAP)  { list1[p] = 0; idx1[0] = p; } }
    }
    if (e >= N_EDGES) return;
    if (ei[N_EDGES + e] == 0) {
        int s = ei[e];
        int p = atomicAdd(deg3, 1); if (p < MAXDEG) eb3[p] = s;
        if (atomicExch(&need2[s], 1) == 0) { int q = atomicAdd(&cnt[1], 1); if (q < T2_CAP) { list2[q] = s; idx2[s] = q; } }
        if (atomicExch(&need1[s], 1) == 0) { int q = atomicAdd(&cnt[0], 1); if (q < T_CAP)  { list1[q] = s; idx1[s] = q; } }
    }
}

// ---------- scan B: edges into need2 -> eb2 buckets; mark need1 sources ----------
__global__ void k_scanB(const int* __restrict__ ei, const int* __restrict__ need2,
                        const int* __restrict__ idx2,
                        int* need1, int* list1, int* idx1, int* cnt,
                        int* eb2, int* deg2) {
    int e = blockIdx.x * blockDim.x + threadIdx.x;
    if (e >= N_EDGES) return;
    int d = ei[N_EDGES + e];
    if (need2[d]) {
        int s = ei[e];
        unsigned t = (unsigned)idx2[d];
        if (t < T2_CAP) { int p = atomicAdd(&deg2[t], 1); if (p < MAXDEG) eb2[t * MAXDEG + p] = s; }
        if (atomicExch(&need1[s], 1) == 0) { int q = atomicAdd(&cnt[0], 1); if (q < T_CAP) { list1[q] = s; idx1[s] = q; } }
    }
}

// ---------- scan C: edges into need1 -> eb1 buckets ----------
__global__ void k_scanC(const int* __restrict__ ei, const int* __restrict__ need1,
                        const int* __restrict__ idx1, int* eb1, int* deg1) {
    int e = blockIdx.x * blockDim.x + threadIdx.x;
    if (e >= N_EDGES) return;
    int d = ei[N_EDGES + e];
    if (need1[d]) {
        unsigned t = (unsigned)idx1[d];
        if (t < T_CAP) { int p = atomicAdd(&deg1[t], 1); if (p < MAXDEG) eb1[t * MAXDEG + p] = ei[e]; }
    }
}

// ---------- node feature: layer 0 encodes from x, later layers load h ----------
template<int LM>
__device__ __forceinline__ float node_h(int i, int lane,
    const float* __restrict__ x, const float* __restrict__ Wn, const float* __restrict__ bn,
    const float* __restrict__ gn, const float* __restrict__ betan,
    const float* __restrict__ hin) {
    if (LM == 0) {
        float acc = bn[lane];
        #pragma unroll
        for (int k = 0; k < FN_DIM; k++) acc += x[i * FN_DIM + k] * Wn[k * HD + lane];
        float v = fmaxf(acc, 0.f);
        float mu = wsum64(v) * (1.f / 64.f);
        float d = v - mu;
        float var = wsum64(d * d) * (1.f / 64.f);
        return d * rsqrtf(var + 1e-5f) * gn[lane] + betan[lane];
    } else {
        return hin[i * HD + lane];
    }
}

// ---------- heads (wave 0 only), writes out[0..32] ----------
__device__ __forceinline__ void heads_eval(float hv, int lane,
    const float* __restrict__ Wq1, const float* __restrict__ bq1,
    const float* __restrict__ gq, const float* __restrict__ betaq,
    const float* __restrict__ Wq2, const float* __restrict__ bq2,
    const float* __restrict__ Wv1, const float* __restrict__ bv1,
    const float* __restrict__ gv, const float* __restrict__ betav,
    const float* __restrict__ Wv2, const float* __restrict__ bv2,
    float* __restrict__ out) {
    float acc = bq1[lane];
    #pragma unroll 8
    for (int k = 0; k < 64; k++) acc += __shfl(hv, k) * Wq1[k * 64 + lane];
    float r = fmaxf(acc, 0.f);
    float mu = wsum64(r) * (1.f / 64.f);
    float d = r - mu;
    float var = wsum64(d * d) * (1.f / 64.f);
    float tq = d * rsqrtf(var + 1e-5f) * gq[lane] + betaq[lane];
    float accv = bv1[lane];
    #pragma unroll 8
    for (int k = 0; k < 64; k++) accv += __shfl(hv, k) * Wv1[k * 64 + lane];
    float rv = fmaxf(accv, 0.f);
    float muv = wsum64(rv) * (1.f / 64.f);
    float dv = rv - muv;
    float varv = wsum64(dv * dv) * (1.f / 64.f);
    float tv = dv * rsqrtf(varv + 1e-5f) * gv[lane] + betav[lane];
    int s = lane & 31;
    float q = bq2[s];
    #pragma unroll 8
    for (int k = 0; k < 64; k++) q += __shfl(tq, k) * Wq2[k * 32 + s];
    if (lane < 32) out[lane] = q;
    float vsum = wsum64(tv * Wv2[lane]);
    if (lane == 0) out[32] = vsum + bv2[0];
}

// ---------- fully fused layer: block per target, 8 waves, 2 edges/wave/pass ----------
// measured-optimal body (r13): unroll-4 weight loops, LM>=1 LDS-stages weights.
template<int LM>
__global__ __launch_bounds__(512) void k_layer(
    const float* __restrict__ x, const float* __restrict__ Wn, const float* __restrict__ bn,
    const float* __restrict__ gn, const float* __restrict__ betan,
    const float* __restrict__ hin,
    const float* __restrict__ Wc1, const float* __restrict__ bc1,
    const float* __restrict__ Wc2, const float* __restrict__ bc2,
    const float* __restrict__ Wg, const float* __restrict__ atts, const float* __restrict__ attd,
    const float* __restrict__ bgv,
    const int* __restrict__ tlist, const int* __restrict__ cntp, int tcap,
    const int* __restrict__ eb, const int* __restrict__ deg,
    float* __restrict__ hout,
    const float* __restrict__ Wq1, const float* __restrict__ bq1,
    const float* __restrict__ gq, const float* __restrict__ betaq,
    const float* __restrict__ Wq2, const float* __restrict__ bq2,
    const float* __restrict__ Wv1, const float* __restrict__ bv1,
    const float* __restrict__ gv, const float* __restrict__ betav,
    const float* __restrict__ Wv2, const float* __restrict__ bv2)
{
    __shared__ float ht[64], ut[64], xgt[64];
    __shared__ float scr[NW][2][64];    // per-wave 2-edge vector scratch
    __shared__ float xgc[MAXDEG][64];   // per-edge xg cache
    __shared__ float ec[MAXDEG];        // per-edge attention logit
    __shared__ float redA[NW][64], redB[NW][64];
    __shared__ float sws[NW];
    __shared__ float sA[2];             // a_s[t], a_d[t]
    __shared__ float sEm;
    // staged weights (LM>=1 only): [0:4096)=Wc1a [4096:8192)=Wc1b [8192:12288)=Wc2 [12288:16384)=Wg
    __shared__ float wst[(LM == 0) ? 4 : 16384];

    int lane = threadIdx.x & 63;
    int wv = threadIdx.x >> 6;          // 0..7
    int ntgt = (LM == 2) ? 1 : min(cntp[0], tcap);

    if constexpr (LM != 0) {
        float4* d4 = (float4*)wst;
        const float4* s1 = (const float4*)Wc1;   // 2048 float4 = both halves
        const float4* s2 = (const float4*)Wc2;
        const float4* s3 = (const float4*)Wg;
        for (int i = threadIdx.x; i < 1024; i += 512) {
            d4[i]        = s1[i];
            d4[1024 + i] = s1[1024 + i];
            d4[2048 + i] = s2[i];
            d4[3072 + i] = s3[i];
        }
        __syncthreads();
    }

    for (int w = blockIdx.x; w < ntgt; w += gridDim.x) {
        int t = (LM == 2) ? 0 : tlist[w];
        if (wv == 0) {
            float h = node_h<LM>(t, lane, x, Wn, bn, gn, betan, hin);
            ht[lane] = h;
            float u = bc1[lane], xg = 0.f;
            if constexpr (LM != 0) {
                #pragma unroll 4
                for (int k = 0; k < 64; k++) {
                    float b = ht[k];
                    u  += b * wst[k * 64 + lane];
                    xg += b * wst[12288 + k * 64 + lane];
                }
            } else {
                #pragma unroll 4
                for (int k = 0; k < 64; k++) {
                    float b = ht[k];
                    u  += b * Wc1[k * 64 + lane];
                    xg += b * Wg[k * 64 + lane];
                }
            }
            ut[lane] = u; xgt[lane] = xg;
            float a_st = wsum64(xg * atts[lane]);
            float a_dt = wsum64(xg * attd[lane]);
            if (lane == 0) { sA[0] = a_st; sA[1] = a_dt; }
        }
        __syncthreads();
        int dg = deg[(LM == 2) ? 0 : w]; if (dg > MAXDEG) dg = MAXDEG;
        float a_dt = sA[1];
        float aggw = -INFINITY;

        for (int base = wv * 2; base < dg; base += 2 * NW) {
            int ne = dg - base; if (ne > 2) ne = 2;
            #pragma unroll
            for (int e = 0; e < 2; e++) {
                if (e < ne) {
                    int s = eb[w * MAXDEG + base + e];
                    scr[wv][e][lane] = node_h<LM>(s, lane, x, Wn, bn, gn, betan, hin);
                }
            }
            float v[2] = {0.f, 0.f};
            float g[2] = {0.f, 0.f};
            if constexpr (LM != 0) {
                #pragma unroll 4
                for (int k = 0; k < 64; k++) {
                    float wc = wst[4096 + k * 64 + lane];
                    float wg = wst[12288 + k * 64 + lane];
                    #pragma unroll
                    for (int e = 0; e < 2; e++) {
                        float b = scr[wv][e][k];
                        v[e] += b * wc;
                        g[e] += b * wg;
                    }
                }
            } else {
                #pragma unroll 4
                for (int k = 0; k < 64; k++) {
                    float wc = Wc1[(64 + k) * 64 + lane];
                    float wg = Wg[k * 64 + lane];
                    #pragma unroll
                    for (int e = 0; e < 2; e++) {
                        float b = scr[wv][e][k];
                        v[e] += b * wc;
                        g[e] += b * wg;
                    }
                }
            }
            float ut_l = ut[lane];
            #pragma unroll
            for (int e = 0; e < 2; e++) scr[wv][e][lane] = fmaxf(ut_l + v[e], 0.f);
            float m[2];
            #pragma unroll
            for (int e = 0; e < 2; e++) m[e] = bc2[lane];
            if constexpr (LM != 0) {
                #pragma unroll 4
                for (int k = 0; k < 64; k++) {
                    float wc2v = wst[8192 + k * 64 + lane];
                    #pragma unroll
                    for (int e = 0; e < 2; e++) m[e] += scr[wv][e][k] * wc2v;
                }
            } else {
                #pragma unroll 4
                for (int k = 0; k < 64; k++) {
                    float wc2v = Wc2[k * 64 + lane];
                    #pragma unroll
                    for (int e = 0; e < 2; e++) m[e] += scr[wv][e][k] * wc2v;
                }
            }
            #pragma unroll
            for (int e = 0; e < 2; e++) {
                if (e < ne) {
                    aggw = fmaxf(aggw, m[e]);
                    int j = base + e;
                    xgc[j][lane] = g[e];
                    float a_ss = wsum64(g[e] * atts[lane]);
                    if (lane == 0) ec[j] = lrelu02(a_ss + a_dt);
                }
            }
        }
        redA[wv][lane] = aggw;
        __syncthreads();

        if (wv == 0) {
            float es = lrelu02(sA[0] + sA[1]);
            float mm = es;
            for (int j = lane; j < dg; j += 64) mm = fmaxf(mm, ec[j]);
            mm = wmax64(mm);
            if (lane == 0) sEm = mm;
        }
        __syncthreads();
        float em = sEm;
        float attv = 0.f, wsv = 0.f;
        for (int j = wv; j < dg; j += NW) {
            float wj = expf(ec[j] - em);
            attv += wj * xgc[j][lane];
            wsv += wj;
        }
        redB[wv][lane] = attv;
        if (lane == 0) sws[wv] = wsv;
        __syncthreads();

        if (wv == 0) {
            float agg = redA[0][lane];
            #pragma unroll
            for (int q = 1; q < NW; q++) agg = fmaxf(agg, redA[q][lane]);
            if (dg == 0) agg = 0.f;   // PyG scatter-max: empty segment -> 0
            float es = lrelu02(sA[0] + sA[1]);
            float wself = expf(es - em);
            float att = wself * xgt[lane];
            float wsum = wself;
            #pragma unroll
            for (int q = 0; q < NW; q++) { att += redB[q][lane]; wsum += sws[q]; }
            float hv = fmaxf(ht[lane] + agg + att / wsum + bgv[lane], 0.f);
            if (LM == 2) {
                heads_eval(hv, lane, Wq1, bq1, gq, betaq, Wq2, bq2,
                           Wv1, bv1, gv, betav, Wv2, bv2, hout);
            } else {
                hout[t * HD + lane] = hv;
            }
        }
        __syncthreads();
    }
}

extern "C" void kernel_launch(void* const* d_in, const int* in_sizes, int n_in,
                              void* d_out, int out_size, void* d_ws, size_t ws_size,
                              hipStream_t stream) {
    const float* x        = (const float*)d_in[0];
    const int*   ei       = (const int*)d_in[1];
    // d_in[2] edge_attr and d_in[7..10] (edge encoder) are dead code in the reference
    const float* Wn       = (const float*)d_in[3];
    const float* bn       = (const float*)d_in[4];
    const float* gn       = (const float*)d_in[5];
    const float* betan    = (const float*)d_in[6];
    const float* Wc1      = (const float*)d_in[11];
    const float* bc1      = (const float*)d_in[12];
    const float* Wc2      = (const float*)d_in[13];
    const float* bc2      = (const float*)d_in[14];
    const float* Wg       = (const float*)d_in[15];
    const float* att_src  = (const float*)d_in[16];
    const float* att_dst  = (const float*)d_in[17];
    const float* bg       = (const float*)d_in[18];
    const float* Wq1      = (const float*)d_in[19];
    const float* bq1      = (const float*)d_in[20];
    const float* gq       = (const float*)d_in[21];
    const float* betaq    = (const float*)d_in[22];
    const float* Wq2      = (const float*)d_in[23];
    const float* bq2      = (const float*)d_in[24];
    const float* Wv1      = (const float*)d_in[25];
    const float* bv1      = (const float*)d_in[26];
    const float* gv       = (const float*)d_in[27];
    const float* betav    = (const float*)d_in[28];
    const float* Wv2      = (const float*)d_in[29];
    const float* bv2      = (const float*)d_in[30];

    // ---- workspace layout (identical ordering to r13)
    float* hB   = (float*)d_ws;                      // h1, N*64
    float* hA   = hB + (size_t)N_NODES * HD;         // h2, N*64
    int* need1  = (int*)(hA + (size_t)N_NODES * HD); // zero-zone start (16B aligned)
    int* need2  = need1 + N_NODES;
    int* deg1   = need2 + N_NODES;                   // T_CAP
    int* deg2   = deg1 + T_CAP;                      // T2_CAP
    int* deg3   = deg2 + T2_CAP;                     // 4
    int* cnt    = deg3 + 4;                          // 8   (zero-zone end)
    int* idx1   = cnt + 8;                           // N
    int* idx2   = idx1 + N_NODES;                    // N
    int* list1  = idx2 + N_NODES;                    // T_CAP
    int* list2  = list1 + T_CAP;                     // T2_CAP
    int* eb1    = list2 + T2_CAP;                    // T_CAP*MAXDEG
    int* eb2    = eb1 + (size_t)T_CAP * MAXDEG;      // T2_CAP*MAXDEG
    int* eb3    = eb2 + (size_t)T2_CAP * MAXDEG;     // MAXDEG

    const int zero_ints = 2 * N_NODES + T_CAP + T2_CAP + 12;   // 108716, /4 exact
    const int n4 = zero_ints / 4;                    // 27179 int4
    const int EB = (N_EDGES + 255) / 256;            // 3125 blocks

    k_zero<<<(n4 + 255) / 256, 256, 0, stream>>>((int4*)need1, n4);
    k_scanA<<<EB, 256, 0, stream>>>(ei, need1, need2, list1, list2,
                                    idx1, idx2, cnt, eb3, deg3);
    k_scanB<<<EB, 256, 0, stream>>>(ei, need2, idx2,
                                    need1, list1, idx1, cnt, eb2, deg2);
    k_scanC<<<EB, 256, 0, stream>>>(ei, need1, idx1, eb1, deg1);

    // layer 0: targets list1 (~355), sources encoded from x on the fly -> hB
    k_layer<0><<<512, 512, 0, stream>>>(
        x, Wn, bn, gn, betan, (const float*)nullptr,
        Wc1 + 0 * 2 * HD * HD, bc1 + 0 * HD, Wc2 + 0 * HD * HD, bc2 + 0 * HD,
        Wg + 0 * HD * HD, att_src + 0 * HD, att_dst + 0 * HD, bg + 0 * HD,
        list1, cnt + 0, T_CAP, eb1, deg1, hB,
        Wq1, bq1, gq, betaq, Wq2, bq2, Wv1, bv1, gv, betav, Wv2, bv2);

    // layer 1: targets list2 (~17), h from hB -> hA
    k_layer<1><<<64, 512, 0, stream>>>(
        x, Wn, bn, gn, betan, hB,
        Wc1 + 1 * 2 * HD * HD, bc1 + 1 * HD, Wc2 + 1 * HD * HD, bc2 + 1 * HD,
        Wg + 1 * HD * HD, att_src + 1 * HD, att_dst + 1 * HD, bg + 1 * HD,
        list2, cnt + 1, T2_CAP, eb2, deg2, hA,
        Wq1, bq1, gq, betaq, Wq2, bq2, Wv1, bv1, gv, betav, Wv2, bv2);

    // layer 2: target {0}, h from hA -> heads -> d_out
    k_layer<2><<<1, 512, 0, stream>>>(
        x, Wn, bn, gn, betan, hA,
        Wc1 + 2 * 2 * HD * HD, bc1 + 2 * HD, Wc2 + 2 * HD * HD, bc2 + 2 * HD,
        Wg + 2 * HD * HD, att_src + 2 * HD, att_dst + 2 * HD, bg + 2 * HD,
        (const int*)nullptr, cnt + 1, 1, eb3, deg3, (float*)d_out,
        Wq1, bq1, gq, betaq, Wq2, bq2, Wv1, bv1, gv, betav, Wv2, bv2);
}